// Round 7
// baseline (1385.365 us; speedup 1.0000x reference)
//
#include <hip/hip_runtime.h>
#include <hip/hip_fp16.h>

#define N_IN   100000
#define N_OUT  200000
#define C_IN   128
#define C_OUT  64
#define NK     27
#define MM     100000
#define BN_EPS 1e-5f

#define TILE_M 128   // scatter3 / fallback tile
#define APAD   136   // fallback LDS row stride (bf16 elems)

// ---- sorted-CSR main path geometry ----
#define TILE_R 100           // output rows per tile (2000*100 == N_OUT)
#define NTILE  2000
#define NSLICE 4             // blocks per tile -> 8000 blocks (scatter3-like TLP)
#define CAP_T  2048          // fixed per-tile record capacity
#define LROW   65            // LDS accumulator row stride (odd -> bank spread)
#define CHCAP  128           // max chunks per tile (CAP_T/16)

typedef short bf16x8 __attribute__((ext_vector_type(8)));
typedef float f32x4  __attribute__((ext_vector_type(4)));

__device__ __forceinline__ unsigned pack2_bf16(float a, float b) {
  unsigned ua = __float_as_uint(a);
  unsigned ub = __float_as_uint(b);
  ua = (ua + 0x7FFFu + ((ua >> 16) & 1u)) >> 16;
  ub = (ub + 0x7FFFu + ((ub >> 16) & 1u)) & 0xFFFF0000u;
  return ua | ub;
}

__device__ __forceinline__ unsigned pack2_f16(float lo, float hi) {
  __half2 h = __floats2half2_rn(lo, hi);
  return *(unsigned*)&h;
}

__device__ __forceinline__ void pk_atomic_f16(const void* addr, unsigned pw) {
  asm volatile("global_atomic_pk_add_f16 %0, %1, off"
               :: "v"((unsigned long long)addr), "v"(pw) : "memory");
}

// Combined converter: x -> xb bf16; weight -> wt [k][co][ci] + wt2 fragment layout
__global__ void convert_kernel(const float* __restrict__ x, unsigned* __restrict__ xb,
                               const float* __restrict__ w, unsigned* __restrict__ wt,
                               unsigned* __restrict__ wt2, int xblocks) {
  if ((int)blockIdx.x < xblocks) {
    int id = blockIdx.x * 256 + threadIdx.x;
    const float4* xs = (const float4*)x;
    float4 v0 = xs[2 * id];
    float4 v1 = xs[2 * id + 1];
    uint4 o;
    o.x = pack2_bf16(v0.x, v0.y);
    o.y = pack2_bf16(v0.z, v0.w);
    o.z = pack2_bf16(v1.x, v1.y);
    o.w = pack2_bf16(v1.z, v1.w);
    ((uint4*)xb)[id] = o;
  } else {
    int pidx = (blockIdx.x - xblocks) * 256 + threadIdx.x;  // [0, 27*4096)
    int k   = pidx >> 12;
    const float* wk = w + (size_t)k * C_IN * C_OUT;
    {  // [k][co][ci] layout (scatter3 / fp32 fallback)
      int rem = pidx & 4095;
      int co  = rem >> 6;
      int ci0 = (rem & 63) * 2;
      wt[pidx] = pack2_bf16(wk[ci0 * C_OUT + co], wk[(ci0 + 1) * C_OUT + co]);
    }
    {  // fragment layout: uint idx = ((k*4+ct)*4+kk)*256 + lane*4 + p
      int p     = pidx & 3;
      int lane6 = (pidx >> 2) & 63;
      int kk    = (pidx >> 8) & 3;
      int ct    = (pidx >> 10) & 3;
      int co  = ct * 16 + (lane6 & 15);
      int ci0 = kk * 32 + (lane6 >> 4) * 8 + p * 2;
      wt2[pidx] = pack2_bf16(wk[ci0 * C_OUT + co], wk[(ci0 + 1) * C_OUT + co]);
    }
  }
}

// ---------- phase A: counting sort of (k,m) pairs by (out_tile, k) ----------
__global__ void hist_kernel(const int* __restrict__ out_map, int* __restrict__ cnt) {
  int m = blockIdx.x * 256 + threadIdx.x;
  int k = blockIdx.y;
  if (m < MM) {
    int o = out_map[k * MM + m];
    atomicAdd(&cnt[(o / TILE_R) * NK + k], 1);
  }
}

// per-tile 27-bin prefix via wave shuffle; tile owns rec[tile*CAP_T ..)
__global__ void tile_scan_kernel(const int* __restrict__ cnt,
                                 int* __restrict__ off,
                                 int* __restrict__ cur) {
  int tile = blockIdx.x * 4 + (threadIdx.x >> 6);
  int lane = threadIdx.x & 63;
  if (tile >= NTILE) return;
  int c = 0;
  if (lane < NK) c = (cnt[tile * NK + lane] + 15) & ~15;   // pad to 16
  int p = c;
  #pragma unroll
  for (int d = 1; d < 32; d <<= 1) {
    int n = __shfl_up(p, d);
    if (lane >= d) p += n;
  }
  int base = tile * CAP_T + p - c;
  if (lane < NK) { off[tile * 28 + lane] = base; cur[tile * 28 + lane] = base; }
  if (lane == NK - 1) off[tile * 28 + NK] = base + c;
}

// rec = (in << 7) | out_local; bit31 set == invalid pad
__global__ void scatter_rec_kernel(const int* __restrict__ in_map,
                                   const int* __restrict__ out_map,
                                   int* __restrict__ cur,
                                   unsigned* __restrict__ rec) {
  int m = blockIdx.x * 256 + threadIdx.x;
  int k = blockIdx.y;
  if (m < MM) {
    int o = out_map[k * MM + m];
    int tile = o / TILE_R;
    int ol = o - tile * TILE_R;
    int pos = atomicAdd(&cur[tile * 28 + k], 1);
    rec[pos] = ((unsigned)in_map[k * MM + m] << 7) | (unsigned)ol;
  }
}

// ---------- phase B: slice gather-GEMM, LDS accumulate, pk-f16 flush ----------
// 8000 blocks (4 slices/tile) x 256 thr: scatter3-shaped TLP.  Straight-line
// per-chunk body (rec -> 4 A-gathers -> 16 MFMA -> shfl + ds_add); waves take
// chunks round-robin (k-monotone, so per-wave B reloads stay rare).  Block
// flushes its private f32 tile once via packed-f16 atomics: 3200/block ->
// 25.6M total vs scatter3's 86.4M (3.4x fewer fabric RMWs).
__global__ __launch_bounds__(256) void conv_slice_kernel(
    const uint4* __restrict__ xb,            // [N_IN][16] 16B-chunks
    const uint4* __restrict__ wt2,           // [k][ct][kk][lane] fragment uint4s
    const unsigned* __restrict__ rec,
    const int* __restrict__ off,
    unsigned short* __restrict__ acc16)
{
  __shared__ float Lacc[TILE_R * LROW];      // 26 KB
  __shared__ int chtab[CHCAP];
  __shared__ int nch_s;

  const int t     = threadIdx.x;
  const int tile  = blockIdx.x >> 2;
  const int slice = blockIdx.x & 3;
  const int wave  = t >> 6;
  const int lane  = t & 63;
  const int quad  = lane >> 4;
  const int l15   = lane & 15;

  for (int i = t; i < TILE_R * LROW; i += 256) Lacc[i] = 0.f;

  if (wave == 0) {
    int cnt = 0, s0 = 0;
    if (lane < NK) {
      s0  = off[tile * 28 + lane];
      cnt = (off[tile * 28 + lane + 1] - s0) >> 4;
    }
    int pos = cnt;
    #pragma unroll
    for (int d = 1; d < 32; d <<= 1) {
      int n = __shfl_up(pos, d);
      if (lane >= d) pos += n;
    }
    int base = pos - cnt;
    for (int i = 0; i < cnt; ++i)
      chtab[base + i] = (lane << 24) | ((s0 + (i << 4)) & 0xFFFFFF);
    if (lane == NK - 1) nch_s = pos;
  }
  __syncthreads();

  const int nch = nch_s;
  const int cs  = (nch * slice) >> 2;
  const int ce  = (nch * (slice + 1)) >> 2;

  int kcur = -1;
  bf16x8 B[4][4];

  for (int ci = cs + wave; ci < ce; ci += 4) {
    unsigned ent = (unsigned)chtab[ci];
    const int k = (int)(ent >> 24);
    unsigned r0 = rec[(ent & 0xFFFFFFu) + l15];
    if (k != kcur) {                         // wave-uniform, k-monotone
      kcur = k;
      const uint4* wkp = wt2 + (size_t)k * 1024 + lane;
      #pragma unroll
      for (int ct = 0; ct < 4; ++ct)
        #pragma unroll
        for (int kk = 0; kk < 4; ++kk)
          B[ct][kk] = *(const bf16x8*)(wkp + (ct * 4 + kk) * 64);
    }
    unsigned row0 = (r0 & 0x80000000u) ? 0u : (r0 >> 7);
    uint4 a[4];
    #pragma unroll
    for (int kk = 0; kk < 4; ++kk) a[kk] = xb[(size_t)row0 * 16 + kk * 4 + quad];

    f32x4 acc0 = (f32x4){0.f,0.f,0.f,0.f};
    f32x4 acc1 = (f32x4){0.f,0.f,0.f,0.f};
    f32x4 acc2 = (f32x4){0.f,0.f,0.f,0.f};
    f32x4 acc3 = (f32x4){0.f,0.f,0.f,0.f};
    #pragma unroll
    for (int kk = 0; kk < 4; ++kk) {
      bf16x8 fa = *(const bf16x8*)&a[kk];
      acc0 = __builtin_amdgcn_mfma_f32_16x16x32_bf16(fa, B[0][kk], acc0, 0, 0, 0);
      acc1 = __builtin_amdgcn_mfma_f32_16x16x32_bf16(fa, B[1][kk], acc1, 0, 0, 0);
      acc2 = __builtin_amdgcn_mfma_f32_16x16x32_bf16(fa, B[2][kk], acc2, 0, 0, 0);
      acc3 = __builtin_amdgcn_mfma_f32_16x16x32_bf16(fa, B[3][kk], acc3, 0, 0, 0);
    }
    // D: col = ct*16 + l15, row = quad*4 + i; rec for row j lives in lane j
    #pragma unroll
    for (int i = 0; i < 4; ++i) {
      unsigned rr = __shfl(r0, quad * 4 + i);
      if (!(rr & 0x80000000u)) {
        float* dst = &Lacc[(rr & 127u) * LROW + l15];
        __hip_atomic_fetch_add(dst +  0, acc0[i], __ATOMIC_RELAXED, __HIP_MEMORY_SCOPE_WORKGROUP);
        __hip_atomic_fetch_add(dst + 16, acc1[i], __ATOMIC_RELAXED, __HIP_MEMORY_SCOPE_WORKGROUP);
        __hip_atomic_fetch_add(dst + 32, acc2[i], __ATOMIC_RELAXED, __HIP_MEMORY_SCOPE_WORKGROUP);
        __hip_atomic_fetch_add(dst + 48, acc3[i], __ATOMIC_RELAXED, __HIP_MEMORY_SCOPE_WORKGROUP);
      }
    }
  }
  __syncthreads();

  // one packed-f16 atomic flush per block (rows not touched add 0.0 -> exact)
  const size_t obase = (size_t)tile * TILE_R * C_OUT;
  for (int idx = t; idx < TILE_R * 32; idx += 256) {
    int r  = idx >> 5;
    int c2 = (idx & 31) << 1;
    unsigned pw = pack2_f16(Lacc[r * LROW + c2], Lacc[r * LROW + c2 + 1]);
    pk_atomic_f16(acc16 + obase + (size_t)r * C_OUT + c2, pw);
  }
}

// ---------- scatter3 (round-0 proven path, used as rich fallback) ----------
__global__ __launch_bounds__(256, 4) void scatter3_kernel(
    const uint4* __restrict__ xb,
    const unsigned short* __restrict__ wt,   // [k][co][ci] bf16
    const int* __restrict__ in_map,
    const int* __restrict__ out_map,
    unsigned short* __restrict__ acc16)
{
  __shared__ unsigned short Bls[C_OUT * APAD];

  const int t = threadIdx.x;
  const int k = blockIdx.y;
  const int mbase = blockIdx.x * TILE_M;

  {
    const uint4* src = (const uint4*)(wt + (size_t)k * C_OUT * C_IN);
    #pragma unroll
    for (int i = 0; i < 4; ++i) {
      int ch  = t + i * 256;
      int co  = ch >> 4;
      int ci0 = (ch & 15) * 8;
      *(uint4*)&Bls[co * APAD + ci0] = src[ch];
    }
  }

  const int wave = t >> 6;
  const int lane = t & 63;
  const int quad = lane >> 4;
  const int l15  = lane & 15;
  const int rb   = wave * 32;

  const int m0 = mbase + rb + l15;
  const int m1 = m0 + 16;
  const int src0 = (m0 < MM) ? in_map[k * MM + m0] : 0;
  const int src1 = (m1 < MM) ? in_map[k * MM + m1] : 0;
  const uint4* xr0 = xb + (size_t)src0 * 16 + quad;
  const uint4* xr1 = xb + (size_t)src1 * 16 + quad;
  uint4 a0[4], a1[4];
  #pragma unroll
  for (int kk = 0; kk < 4; ++kk) {
    a0[kk] = xr0[kk * 4];
    a1[kk] = xr1[kk * 4];
  }

  __syncthreads();

  f32x4 acc[2][4];
  #pragma unroll
  for (int i = 0; i < 2; ++i)
    #pragma unroll
    for (int j = 0; j < 4; ++j)
      acc[i][j] = (f32x4){0.f, 0.f, 0.f, 0.f};

  #pragma unroll
  for (int kk = 0; kk < 4; ++kk) {
    const int koff = kk * 32 + quad * 8;
    bf16x8 fa0 = *(const bf16x8*)&a0[kk];
    bf16x8 fa1 = *(const bf16x8*)&a1[kk];
    bf16x8 b0 = *(const bf16x8*)&Bls[(l15) * APAD + koff];
    bf16x8 b1 = *(const bf16x8*)&Bls[(16 + l15) * APAD + koff];
    bf16x8 b2 = *(const bf16x8*)&Bls[(32 + l15) * APAD + koff];
    bf16x8 b3 = *(const bf16x8*)&Bls[(48 + l15) * APAD + koff];
    acc[0][0] = __builtin_amdgcn_mfma_f32_16x16x32_bf16(fa0, b0, acc[0][0], 0, 0, 0);
    acc[0][1] = __builtin_amdgcn_mfma_f32_16x16x32_bf16(fa0, b1, acc[0][1], 0, 0, 0);
    acc[0][2] = __builtin_amdgcn_mfma_f32_16x16x32_bf16(fa0, b2, acc[0][2], 0, 0, 0);
    acc[0][3] = __builtin_amdgcn_mfma_f32_16x16x32_bf16(fa0, b3, acc[0][3], 0, 0, 0);
    acc[1][0] = __builtin_amdgcn_mfma_f32_16x16x32_bf16(fa1, b0, acc[1][0], 0, 0, 0);
    acc[1][1] = __builtin_amdgcn_mfma_f32_16x16x32_bf16(fa1, b1, acc[1][1], 0, 0, 0);
    acc[1][2] = __builtin_amdgcn_mfma_f32_16x16x32_bf16(fa1, b2, acc[1][2], 0, 0, 0);
    acc[1][3] = __builtin_amdgcn_mfma_f32_16x16x32_bf16(fa1, b3, acc[1][3], 0, 0, 0);
  }

  const int par = l15 & 1;
  #pragma unroll
  for (int rt = 0; rt < 2; ++rt) {
    int rloc = rb + rt * 16 + quad * 4;
    int mrow = mbase + rloc;
    int4 o4;
    if (mrow + 3 < MM) {
      o4 = *(const int4*)(out_map + (size_t)k * MM + mrow);
    } else {
      o4.x = (mrow + 0 < MM) ? out_map[(size_t)k * MM + mrow + 0] : 0;
      o4.y = (mrow + 1 < MM) ? out_map[(size_t)k * MM + mrow + 1] : 0;
      o4.z = (mrow + 2 < MM) ? out_map[(size_t)k * MM + mrow + 2] : 0;
      o4.w = (mrow + 3 < MM) ? out_map[(size_t)k * MM + mrow + 3] : 0;
    }
    int om4[4] = {o4.x, o4.y, o4.z, o4.w};
    #pragma unroll
    for (int ct = 0; ct < 4; ++ct) {
      f32x4 v = acc[rt][ct];
      int colb = ct * 16 + (l15 & ~1);
      #pragma unroll
      for (int i = 0; i < 4; ++i) {
        float vn = __shfl_xor(v[i], 1);
        float lo = par ? vn : v[i];
        float hi = par ? v[i] : vn;
        unsigned pw = pack2_f16(lo, hi);
        if (((i & 1) == par) && (mrow + i < MM)) {
          const unsigned short* addr = acc16 + (size_t)om4[i] * C_OUT + colb;
          pk_atomic_f16(addr, pw);
        }
      }
    }
  }
}

// ---------- legacy fp32 fallback ----------
__global__ __launch_bounds__(256) void scatter_f32_kernel(
    const float* __restrict__ x,
    const unsigned short* __restrict__ wt,
    const int* __restrict__ in_map,
    const int* __restrict__ out_map,
    float* __restrict__ outf)
{
  __shared__ unsigned short Als[TILE_M * APAD];
  __shared__ unsigned short Bls[C_OUT * APAD];
  __shared__ int om[TILE_M];

  const int t = threadIdx.x;
  const int k = blockIdx.y;
  const int mbase = blockIdx.x * TILE_M;

  if (t < TILE_M) {
    int m = mbase + t;
    om[t] = (m < MM) ? out_map[k * MM + m] : 0;
  }
  {
    const uint4* src = (const uint4*)(wt + (size_t)k * C_OUT * C_IN);
    #pragma unroll
    for (int i = 0; i < 4; ++i) {
      int ch  = t + i * 256;
      int co  = ch >> 4;
      int ci0 = (ch & 15) * 8;
      *(uint4*)&Bls[co * APAD + ci0] = src[ch];
    }
  }
  {
    int r    = t >> 1;
    int half = t & 1;
    int m    = mbase + r;
    int src  = (m < MM) ? in_map[k * MM + m] : 0;
    const float4* xr = (const float4*)(x + (size_t)src * C_IN) + half * 16;
    uint2* dst = (uint2*)&Als[r * APAD + half * 64];
    #pragma unroll
    for (int j = 0; j < 16; ++j) {
      float4 v = xr[j];
      dst[j] = make_uint2(pack2_bf16(v.x, v.y), pack2_bf16(v.z, v.w));
    }
  }
  __syncthreads();

  const int wave = t >> 6;
  const int lane = t & 63;
  const int quad = lane >> 4;
  const int l15  = lane & 15;
  const int rb   = wave * 32;

  f32x4 acc[2][4];
  #pragma unroll
  for (int i = 0; i < 2; ++i)
    #pragma unroll
    for (int j = 0; j < 4; ++j)
      acc[i][j] = (f32x4){0.f, 0.f, 0.f, 0.f};

  #pragma unroll
  for (int kk = 0; kk < 4; ++kk) {
    const int koff = kk * 32 + quad * 8;
    bf16x8 a0 = *(const bf16x8*)&Als[(rb + l15) * APAD + koff];
    bf16x8 a1 = *(const bf16x8*)&Als[(rb + 16 + l15) * APAD + koff];
    bf16x8 b0 = *(const bf16x8*)&Bls[(l15) * APAD + koff];
    bf16x8 b1 = *(const bf16x8*)&Bls[(16 + l15) * APAD + koff];
    bf16x8 b2 = *(const bf16x8*)&Bls[(32 + l15) * APAD + koff];
    bf16x8 b3 = *(const bf16x8*)&Bls[(48 + l15) * APAD + koff];
    acc[0][0] = __builtin_amdgcn_mfma_f32_16x16x32_bf16(a0, b0, acc[0][0], 0, 0, 0);
    acc[0][1] = __builtin_amdgcn_mfma_f32_16x16x32_bf16(a0, b1, acc[0][1], 0, 0, 0);
    acc[0][2] = __builtin_amdgcn_mfma_f32_16x16x32_bf16(a0, b2, acc[0][2], 0, 0, 0);
    acc[0][3] = __builtin_amdgcn_mfma_f32_16x16x32_bf16(a0, b3, acc[0][3], 0, 0, 0);
    acc[1][0] = __builtin_amdgcn_mfma_f32_16x16x32_bf16(a1, b0, acc[1][0], 0, 0, 0);
    acc[1][1] = __builtin_amdgcn_mfma_f32_16x16x32_bf16(a1, b1, acc[1][1], 0, 0, 0);
    acc[1][2] = __builtin_amdgcn_mfma_f32_16x16x32_bf16(a1, b2, acc[1][2], 0, 0, 0);
    acc[1][3] = __builtin_amdgcn_mfma_f32_16x16x32_bf16(a1, b3, acc[1][3], 0, 0, 0);
  }

  #pragma unroll
  for (int rt = 0; rt < 2; ++rt) {
    int rloc = rb + rt * 16 + quad * 4;
    int4 o4 = *(const int4*)&om[rloc];
    int mrow = mbase + rloc;
    #pragma unroll
    for (int ct = 0; ct < 4; ++ct) {
      f32x4 v = acc[rt][ct];
      int col = ct * 16 + l15;
      if (mrow + 0 < MM) unsafeAtomicAdd(&outf[(size_t)o4.x * C_OUT + col], v[0]);
      if (mrow + 1 < MM) unsafeAtomicAdd(&outf[(size_t)o4.y * C_OUT + col], v[1]);
      if (mrow + 2 < MM) unsafeAtomicAdd(&outf[(size_t)o4.z * C_OUT + col], v[2]);
      if (mrow + 3 < MM) unsafeAtomicAdd(&outf[(size_t)o4.w * C_OUT + col], v[3]);
    }
  }
}

// ---------- f16-accumulator reductions ----------
__global__ __launch_bounds__(256) void stats16_kernel(const unsigned* __restrict__ acc,
                                                      float* __restrict__ ws) {
  __shared__ float red[4][8][32];
  int t = threadIdx.x;
  int w = t & 31, sub = t >> 5;
  float s0 = 0, q0 = 0, s1 = 0, q1 = 0;
  for (int r = blockIdx.x * 8 + sub; r < N_OUT; r += gridDim.x * 8) {
    unsigned u = acc[(size_t)r * 32 + w];
    __half2 h = *(__half2*)&u;
    float a = __low2float(h), b = __high2float(h);
    s0 += a; q0 += a * a; s1 += b; q1 += b * b;
  }
  red[0][sub][w] = s0; red[1][sub][w] = q0;
  red[2][sub][w] = s1; red[3][sub][w] = q1;
  __syncthreads();
  if (t < 32) {
    float S0 = 0, Q0 = 0, S1 = 0, Q1 = 0;
    #pragma unroll
    for (int s = 0; s < 8; ++s) {
      S0 += red[0][s][t]; Q0 += red[1][s][t];
      S1 += red[2][s][t]; Q1 += red[3][s][t];
    }
    unsafeAtomicAdd(&ws[2 * t],      S0);
    unsafeAtomicAdd(&ws[64 + 2 * t], Q0);
    unsafeAtomicAdd(&ws[2 * t + 1],      S1);
    unsafeAtomicAdd(&ws[64 + 2 * t + 1], Q1);
  }
}

__global__ void finalize16_kernel(const uint2* __restrict__ acc,
                                  float* __restrict__ out,
                                  const float* __restrict__ ws) {
  int i = blockIdx.x * 256 + threadIdx.x;
  uint2 u = acc[i];
  __half2 h0 = *(__half2*)&u.x;
  __half2 h1 = *(__half2*)&u.y;
  int c0 = (i & 15) * 4;
  float s0 = ws[128 + c0], s1 = ws[129 + c0], s2 = ws[130 + c0], s3 = ws[131 + c0];
  float b0 = ws[192 + c0], b1 = ws[193 + c0], b2 = ws[194 + c0], b3 = ws[195 + c0];
  float4 v;
  v.x = fmaxf(fmaf(__low2float(h0),  s0, b0), 0.f);
  v.y = fmaxf(fmaf(__high2float(h0), s1, b1), 0.f);
  v.z = fmaxf(fmaf(__low2float(h1),  s2, b2), 0.f);
  v.w = fmaxf(fmaf(__high2float(h1), s3, b3), 0.f);
  ((float4*)out)[i] = v;
}

// ---------- fp32 fallback reductions ----------
__global__ void stats_kernel(const float* __restrict__ out, float* __restrict__ ws) {
  __shared__ float ls[4][64];
  __shared__ float ls2[4][64];
  int t = threadIdx.x;
  int c = t & 63, sub = t >> 6;
  float s = 0.f, s2 = 0.f;
  for (int r = blockIdx.x * 4 + sub; r < N_OUT; r += gridDim.x * 4) {
    float v = out[(size_t)r * C_OUT + c];
    s += v; s2 += v * v;
  }
  ls[sub][c] = s; ls2[sub][c] = s2;
  __syncthreads();
  if (t < 64) {
    float ts = ls[0][t] + ls[1][t] + ls[2][t] + ls[3][t];
    float t2 = ls2[0][t] + ls2[1][t] + ls2[2][t] + ls2[3][t];
    unsafeAtomicAdd(&ws[t], ts);
    unsafeAtomicAdd(&ws[64 + t], t2);
  }
}

__global__ void finalize_kernel(float* __restrict__ out, const float* __restrict__ ws) {
  int i = blockIdx.x * 256 + threadIdx.x;
  float4 v = ((const float4*)out)[i];
  int c0 = (i & 15) * 4;
  float s0 = ws[128 + c0], s1 = ws[129 + c0], s2 = ws[130 + c0], s3 = ws[131 + c0];
  float b0 = ws[192 + c0], b1 = ws[193 + c0], b2 = ws[194 + c0], b3 = ws[195 + c0];
  v.x = fmaxf(fmaf(v.x, s0, b0), 0.f);
  v.y = fmaxf(fmaf(v.y, s1, b1), 0.f);
  v.z = fmaxf(fmaf(v.z, s2, b2), 0.f);
  v.w = fmaxf(fmaf(v.w, s3, b3), 0.f);
  ((float4*)out)[i] = v;
}

__global__ void prep_kernel(float* __restrict__ ws,
                            const float* __restrict__ gamma,
                            const float* __restrict__ beta) {
  int c = threadIdx.x;
  float mean = ws[c] * (1.0f / N_OUT);
  float var  = ws[64 + c] * (1.0f / N_OUT) - mean * mean;
  var = fmaxf(var, 0.0f);
  float sc = gamma[c] * rsqrtf(var + BN_EPS);
  ws[128 + c] = sc;
  ws[192 + c] = beta[c] - mean * sc;
}

extern "C" void kernel_launch(void* const* d_in, const int* in_sizes, int n_in,
                              void* d_out, int out_size, void* d_ws, size_t ws_size,
                              hipStream_t stream) {
  const float* x      = (const float*)d_in[0];
  const float* weight = (const float*)d_in[1];
  const float* gamma  = (const float*)d_in[2];
  const float* beta   = (const float*)d_in[3];
  const int* in_map   = (const int*)d_in[4];
  const int* out_map  = (const int*)d_in[5];
  float* out   = (float*)d_out;
  float* stats = (float*)d_ws;

  const size_t WT_OFF  = 4096;                       // 442 KB [k][co][ci]
  const size_t WT2_OFF = 512u * 1024;                // 442 KB fragment layout
  const size_t CNT_OFF = 1024u * 1024;               // 216 KB [tile][27]
  const size_t OFF_OFF = 1280u * 1024;               // 224 KB [tile][28]
  const size_t CUR_OFF = 1536u * 1024;               // 224 KB [tile][28]
  const size_t XB_OFF  = 2u * 1024 * 1024;           // 25.6 MB bf16 x
  const size_t XB_SZ   = (size_t)N_IN * C_IN * 2;
  const size_t REC_OFF = 28u * 1024 * 1024;          // 16.4 MB records
  const size_t REC_SZ  = (size_t)NTILE * CAP_T * 4;
  const size_t ACC_SZ  = (size_t)N_OUT * C_OUT * 2;  // 25.6 MB f16 accumulator
  const size_t ACC_MAIN = 45u * 1024 * 1024;
  const size_t NEED_MAIN = ACC_MAIN + ACC_SZ;        // ~70.6 MB
  const size_t ACC_S3   = REC_OFF;                   // scatter3: acc over rec region
  const size_t NEED_S3  = ACC_S3 + ACC_SZ;           // ~53.6 MB

  unsigned* wt  = (unsigned*)((char*)d_ws + WT_OFF);
  unsigned* wt2 = (unsigned*)((char*)d_ws + WT2_OFF);
  int* cnt      = (int*)((char*)d_ws + CNT_OFF);
  int* off      = (int*)((char*)d_ws + OFF_OFF);
  int* cur      = (int*)((char*)d_ws + CUR_OFF);
  unsigned* xb  = (unsigned*)((char*)d_ws + XB_OFF);
  unsigned* rec = (unsigned*)((char*)d_ws + REC_OFF);

  hipMemsetAsync(d_ws, 0, 1024, stream);

  if (ws_size >= NEED_MAIN) {
    unsigned short* acc16 = (unsigned short*)((char*)d_ws + ACC_MAIN);
    hipMemsetAsync(cnt, 0, (size_t)NTILE * NK * sizeof(int), stream);
    hipMemsetAsync(rec, 0x80, REC_SZ, stream);       // pad slots invalid
    hipMemsetAsync(acc16, 0, ACC_SZ, stream);
    convert_kernel<<<6682, 256, 0, stream>>>(x, xb, weight, wt, wt2, 6250);
    hist_kernel<<<dim3((MM + 255) / 256, NK), 256, 0, stream>>>(out_map, cnt);
    tile_scan_kernel<<<(NTILE + 3) / 4, 256, 0, stream>>>(cnt, off, cur);
    scatter_rec_kernel<<<dim3((MM + 255) / 256, NK), 256, 0, stream>>>(
        in_map, out_map, cur, rec);
    conv_slice_kernel<<<NTILE * NSLICE, 256, 0, stream>>>((const uint4*)xb,
        (const uint4*)wt2, rec, off, acc16);
    stats16_kernel<<<1024, 256, 0, stream>>>((const unsigned*)acc16, stats);
    prep_kernel<<<1, 64, 0, stream>>>(stats, gamma, beta);
    finalize16_kernel<<<(N_OUT * C_OUT / 4 + 255) / 256, 256, 0, stream>>>(
        (const uint2*)acc16, out, stats);
  } else if (ws_size >= NEED_S3) {
    // round-0 proven scatter3 path
    unsigned short* acc16 = (unsigned short*)((char*)d_ws + ACC_S3);
    hipMemsetAsync(acc16, 0, ACC_SZ, stream);
    convert_kernel<<<6682, 256, 0, stream>>>(x, xb, weight, wt, wt2, 6250);
    dim3 g((MM + TILE_M - 1) / TILE_M, NK);
    scatter3_kernel<<<g, 256, 0, stream>>>((const uint4*)xb,
        (const unsigned short*)wt, in_map, out_map, acc16);
    stats16_kernel<<<1024, 256, 0, stream>>>((const unsigned*)acc16, stats);
    prep_kernel<<<1, 64, 0, stream>>>(stats, gamma, beta);
    finalize16_kernel<<<(N_OUT * C_OUT / 4 + 255) / 256, 256, 0, stream>>>(
        (const uint2*)acc16, out, stats);
  } else {
    // last-resort fp32 path
    hipMemsetAsync(d_out, 0, (size_t)N_OUT * C_OUT * sizeof(float), stream);
    convert_kernel<<<432, 256, 0, stream>>>(x, xb, weight, wt, wt2, 0);
    dim3 g((MM + TILE_M - 1) / TILE_M, NK);
    scatter_f32_kernel<<<g, 256, 0, stream>>>(x, (const unsigned short*)wt,
                                              in_map, out_map, out);
    stats_kernel<<<512, 256, 0, stream>>>(out, stats);
    prep_kernel<<<1, 64, 0, stream>>>(stats, gamma, beta);
    finalize_kernel<<<(N_OUT * C_OUT / 4 + 255) / 256, 256, 0, stream>>>(out, stats);
  }
}

// Round 8
// 1067.868 us; speedup vs baseline: 1.2973x; 1.2973x over previous
//
#include <hip/hip_runtime.h>
#include <hip/hip_fp16.h>

#define N_IN   100000
#define N_OUT  200000
#define C_IN   128
#define C_OUT  64
#define NK     27
#define MM     100000
#define BN_EPS 1e-5f

#define TILE_M 128   // scatter3 / fallback tile
#define APAD   136   // fallback LDS row stride (bf16 elems)

// ---- input-major sorted path geometry ----
#define BUK_ROWS 128          // x-rows per bucket
#define NBUK     782          // ceil(100000/128)
#define CAP_B    4608         // padded records per bucket (mean ~3660, +12 sigma)
#define CHCAP2   288          // max chunks per bucket (CAP_B/16)
#define XROW     17           // LDS row stride in uint4 (272 B -> <=2-way banks)

typedef short bf16x8 __attribute__((ext_vector_type(8)));
typedef float f32x4  __attribute__((ext_vector_type(4)));

__device__ __forceinline__ unsigned pack2_bf16(float a, float b) {
  unsigned ua = __float_as_uint(a);
  unsigned ub = __float_as_uint(b);
  ua = (ua + 0x7FFFu + ((ua >> 16) & 1u)) >> 16;
  ub = (ub + 0x7FFFu + ((ub >> 16) & 1u)) & 0xFFFF0000u;
  return ua | ub;
}

__device__ __forceinline__ unsigned pack2_f16(float lo, float hi) {
  __half2 h = __floats2half2_rn(lo, hi);
  return *(unsigned*)&h;
}

__device__ __forceinline__ void pk_atomic_f16(const void* addr, unsigned pw) {
  asm volatile("global_atomic_pk_add_f16 %0, %1, off"
               :: "v"((unsigned long long)addr), "v"(pw) : "memory");
}

// Combined converter: x -> xb bf16; weight -> wt [k][co][ci] + wt2 fragment layout
__global__ void convert_kernel(const float* __restrict__ x, unsigned* __restrict__ xb,
                               const float* __restrict__ w, unsigned* __restrict__ wt,
                               unsigned* __restrict__ wt2, int xblocks) {
  if ((int)blockIdx.x < xblocks) {
    int id = blockIdx.x * 256 + threadIdx.x;
    const float4* xs = (const float4*)x;
    float4 v0 = xs[2 * id];
    float4 v1 = xs[2 * id + 1];
    uint4 o;
    o.x = pack2_bf16(v0.x, v0.y);
    o.y = pack2_bf16(v0.z, v0.w);
    o.z = pack2_bf16(v1.x, v1.y);
    o.w = pack2_bf16(v1.z, v1.w);
    ((uint4*)xb)[id] = o;
  } else {
    int pidx = (blockIdx.x - xblocks) * 256 + threadIdx.x;  // [0, 27*4096)
    int k   = pidx >> 12;
    const float* wk = w + (size_t)k * C_IN * C_OUT;
    {  // [k][co][ci] layout (scatter3 / fp32 fallback)
      int rem = pidx & 4095;
      int co  = rem >> 6;
      int ci0 = (rem & 63) * 2;
      wt[pidx] = pack2_bf16(wk[ci0 * C_OUT + co], wk[(ci0 + 1) * C_OUT + co]);
    }
    {  // fragment layout: uint idx = ((k*4+ct)*4+kk)*256 + lane*4 + p
      int p     = pidx & 3;
      int lane6 = (pidx >> 2) & 63;
      int kk    = (pidx >> 8) & 3;
      int ct    = (pidx >> 10) & 3;
      int co  = ct * 16 + (lane6 & 15);
      int ci0 = kk * 32 + (lane6 >> 4) * 8 + p * 2;
      wt2[pidx] = pack2_bf16(wk[ci0 * C_OUT + co], wk[(ci0 + 1) * C_OUT + co]);
    }
  }
}

// ---------- phase A: counting sort of (k,m) pairs by (in_bucket, k) ----------
__global__ void hist_in_kernel(const int* __restrict__ in_map, int* __restrict__ cnt) {
  int m = blockIdx.x * 256 + threadIdx.x;
  int k = blockIdx.y;
  if (m < MM) {
    int i = in_map[k * MM + m];
    atomicAdd(&cnt[(i >> 7) * NK + k], 1);
  }
}

// per-bucket 27-bin prefix via wave shuffle; bucket owns rec[buk*CAP_B ..)
__global__ void buk_scan_kernel(const int* __restrict__ cnt,
                                int* __restrict__ off,
                                int* __restrict__ cur) {
  int buk  = blockIdx.x * 4 + (threadIdx.x >> 6);
  int lane = threadIdx.x & 63;
  if (buk >= NBUK) return;
  int c = 0;
  if (lane < NK) c = (cnt[buk * NK + lane] + 15) & ~15;   // pad to 16
  int p = c;
  #pragma unroll
  for (int d = 1; d < 32; d <<= 1) {
    int n = __shfl_up(p, d);
    if (lane >= d) p += n;
  }
  int base = buk * CAP_B + p - c;
  if (lane < NK) { off[buk * 28 + lane] = base; cur[buk * 28 + lane] = base; }
  if (lane == NK - 1) off[buk * 28 + NK] = base + c;
}

// rec = (out << 7) | in_local; bit31 set == invalid pad
__global__ void scatter_rec_in_kernel(const int* __restrict__ in_map,
                                      const int* __restrict__ out_map,
                                      int* __restrict__ cur,
                                      unsigned* __restrict__ rec) {
  int m = blockIdx.x * 256 + threadIdx.x;
  int k = blockIdx.y;
  if (m < MM) {
    int iin = in_map[k * MM + m];
    int buk = iin >> 7;
    int pos = atomicAdd(&cur[buk * 28 + k], 1);
    rec[pos] = ((unsigned)out_map[k * MM + m] << 7) | (unsigned)(iin & 127);
  }
}

// ---------- phase B: input-major gather-GEMM ----------
// One block per 128-row x-bucket.  The bucket's rows are staged into LDS ONCE
// (32 KB streaming read -> x gathered 25.6 MB total instead of 691 MB of
// random-row traffic, the shared wall of rounds 0-7).  Chunks of 16 k-sorted
// pairs: sequential rec read, A-fragments from LDS, B per k-segment from the
// coalesced wt2 image, 16 MFMAs, scatter3's paired pk-f16 atomic epilogue.
__global__ __launch_bounds__(256) void conv_in_kernel(
    const uint4* __restrict__ xb,            // [N_IN][16] 16B-chunks
    const uint4* __restrict__ wt2,           // [k][ct][kk][lane] fragment uint4s
    const unsigned* __restrict__ rec,
    const int* __restrict__ off,
    unsigned short* __restrict__ acc16)
{
  __shared__ uint4 Lrows[BUK_ROWS * XROW];   // 34.8 KB
  __shared__ int chtab[CHCAP2];
  __shared__ int nch_s;

  const int t    = threadIdx.x;
  const int buk  = blockIdx.x;
  const int wave = t >> 6;
  const int lane = t & 63;
  const int quad = lane >> 4;
  const int l15  = lane & 15;

  // stage the bucket's 128 x-rows (contiguous -> fully coalesced)
  {
    const int rbase = buk * BUK_ROWS;
    #pragma unroll
    for (int it = 0; it < 8; ++it) {
      int idx = t + it * 256;                // 0..2047
      int row = idx >> 4, c = idx & 15;
      int grow = rbase + row;
      uint4 v = make_uint4(0u, 0u, 0u, 0u);
      if (grow < N_IN) v = xb[(size_t)grow * 16 + c];
      Lrows[row * XROW + c] = v;
    }
  }
  // chunk table (k-sorted since bins are k-ordered)
  if (wave == 0) {
    int cnt = 0, s0 = 0;
    if (lane < NK) {
      s0  = off[buk * 28 + lane];
      cnt = (off[buk * 28 + lane + 1] - s0) >> 4;
    }
    int pos = cnt;
    #pragma unroll
    for (int d = 1; d < 32; d <<= 1) {
      int n = __shfl_up(pos, d);
      if (lane >= d) pos += n;
    }
    int base = pos - cnt;
    for (int i = 0; i < cnt; ++i)
      chtab[base + i] = (lane << 24) | (s0 + (i << 4));   // abs rec idx < 2^24
    if (lane == NK - 1) nch_s = pos;
  }
  __syncthreads();

  const int nch = nch_s;
  const int cs  = (nch * wave) >> 2;
  const int ce  = (nch * (wave + 1)) >> 2;
  const int par = l15 & 1;

  int kcur = -1;
  bf16x8 B[4][4];

  for (int ci = cs; ci < ce; ++ci) {
    unsigned ent = (unsigned)chtab[ci];
    const int k = (int)(ent >> 24);
    unsigned r0 = rec[(ent & 0xFFFFFFu) + l15];    // coalesced 64B
    if (k != kcur) {                               // wave-uniform
      kcur = k;
      const uint4* wkp = wt2 + (size_t)k * 1024 + lane;
      #pragma unroll
      for (int ct = 0; ct < 4; ++ct)
        #pragma unroll
        for (int kk = 0; kk < 4; ++kk)
          B[ct][kk] = *(const bf16x8*)(wkp + (ct * 4 + kk) * 64);
    }
    const int in_l = (int)(r0 & 127u);
    bf16x8 fa[4];
    #pragma unroll
    for (int kk = 0; kk < 4; ++kk)
      fa[kk] = *(const bf16x8*)&Lrows[in_l * XROW + kk * 4 + quad];

    f32x4 acc0 = (f32x4){0.f,0.f,0.f,0.f};
    f32x4 acc1 = (f32x4){0.f,0.f,0.f,0.f};
    f32x4 acc2 = (f32x4){0.f,0.f,0.f,0.f};
    f32x4 acc3 = (f32x4){0.f,0.f,0.f,0.f};
    #pragma unroll
    for (int kk = 0; kk < 4; ++kk) {
      acc0 = __builtin_amdgcn_mfma_f32_16x16x32_bf16(fa[kk], B[0][kk], acc0, 0, 0, 0);
      acc1 = __builtin_amdgcn_mfma_f32_16x16x32_bf16(fa[kk], B[1][kk], acc1, 0, 0, 0);
      acc2 = __builtin_amdgcn_mfma_f32_16x16x32_bf16(fa[kk], B[2][kk], acc2, 0, 0, 0);
      acc3 = __builtin_amdgcn_mfma_f32_16x16x32_bf16(fa[kk], B[3][kk], acc3, 0, 0, 0);
    }
    // D: col = ct*16 + l15, row = quad*4 + i; rec for row j lives in lane j.
    // Paired pk-f16 atomics (scatter3-proven): shfl_xor pairs cols c,c^1.
    #pragma unroll
    for (int i = 0; i < 4; ++i) {
      unsigned rr = __shfl(r0, quad * 4 + i);
      bool ok = ((i & 1) == par) && !(rr & 0x80000000u);
      const unsigned short* abase = acc16 + (size_t)(rr >> 7) * C_OUT + (l15 & ~1);
      float vn0 = __shfl_xor(acc0[i], 1);
      unsigned p0 = pack2_f16(par ? vn0 : acc0[i], par ? acc0[i] : vn0);
      if (ok) pk_atomic_f16(abase +  0, p0);
      float vn1 = __shfl_xor(acc1[i], 1);
      unsigned p1 = pack2_f16(par ? vn1 : acc1[i], par ? acc1[i] : vn1);
      if (ok) pk_atomic_f16(abase + 16, p1);
      float vn2 = __shfl_xor(acc2[i], 1);
      unsigned p2 = pack2_f16(par ? vn2 : acc2[i], par ? acc2[i] : vn2);
      if (ok) pk_atomic_f16(abase + 32, p2);
      float vn3 = __shfl_xor(acc3[i], 1);
      unsigned p3 = pack2_f16(par ? vn3 : acc3[i], par ? acc3[i] : vn3);
      if (ok) pk_atomic_f16(abase + 48, p3);
    }
  }
}

// ---------- scatter3 (round-0 proven path, rich fallback) ----------
__global__ __launch_bounds__(256, 4) void scatter3_kernel(
    const uint4* __restrict__ xb,
    const unsigned short* __restrict__ wt,   // [k][co][ci] bf16
    const int* __restrict__ in_map,
    const int* __restrict__ out_map,
    unsigned short* __restrict__ acc16)
{
  __shared__ unsigned short Bls[C_OUT * APAD];

  const int t = threadIdx.x;
  const int k = blockIdx.y;
  const int mbase = blockIdx.x * TILE_M;

  {
    const uint4* src = (const uint4*)(wt + (size_t)k * C_OUT * C_IN);
    #pragma unroll
    for (int i = 0; i < 4; ++i) {
      int ch  = t + i * 256;
      int co  = ch >> 4;
      int ci0 = (ch & 15) * 8;
      *(uint4*)&Bls[co * APAD + ci0] = src[ch];
    }
  }

  const int wave = t >> 6;
  const int lane = t & 63;
  const int quad = lane >> 4;
  const int l15  = lane & 15;
  const int rb   = wave * 32;

  const int m0 = mbase + rb + l15;
  const int m1 = m0 + 16;
  const int src0 = (m0 < MM) ? in_map[k * MM + m0] : 0;
  const int src1 = (m1 < MM) ? in_map[k * MM + m1] : 0;
  const uint4* xr0 = xb + (size_t)src0 * 16 + quad;
  const uint4* xr1 = xb + (size_t)src1 * 16 + quad;
  uint4 a0[4], a1[4];
  #pragma unroll
  for (int kk = 0; kk < 4; ++kk) {
    a0[kk] = xr0[kk * 4];
    a1[kk] = xr1[kk * 4];
  }

  __syncthreads();

  f32x4 acc[2][4];
  #pragma unroll
  for (int i = 0; i < 2; ++i)
    #pragma unroll
    for (int j = 0; j < 4; ++j)
      acc[i][j] = (f32x4){0.f, 0.f, 0.f, 0.f};

  #pragma unroll
  for (int kk = 0; kk < 4; ++kk) {
    const int koff = kk * 32 + quad * 8;
    bf16x8 fa0 = *(const bf16x8*)&a0[kk];
    bf16x8 fa1 = *(const bf16x8*)&a1[kk];
    bf16x8 b0 = *(const bf16x8*)&Bls[(l15) * APAD + koff];
    bf16x8 b1 = *(const bf16x8*)&Bls[(16 + l15) * APAD + koff];
    bf16x8 b2 = *(const bf16x8*)&Bls[(32 + l15) * APAD + koff];
    bf16x8 b3 = *(const bf16x8*)&Bls[(48 + l15) * APAD + koff];
    acc[0][0] = __builtin_amdgcn_mfma_f32_16x16x32_bf16(fa0, b0, acc[0][0], 0, 0, 0);
    acc[0][1] = __builtin_amdgcn_mfma_f32_16x16x32_bf16(fa0, b1, acc[0][1], 0, 0, 0);
    acc[0][2] = __builtin_amdgcn_mfma_f32_16x16x32_bf16(fa0, b2, acc[0][2], 0, 0, 0);
    acc[0][3] = __builtin_amdgcn_mfma_f32_16x16x32_bf16(fa0, b3, acc[0][3], 0, 0, 0);
    acc[1][0] = __builtin_amdgcn_mfma_f32_16x16x32_bf16(fa1, b0, acc[1][0], 0, 0, 0);
    acc[1][1] = __builtin_amdgcn_mfma_f32_16x16x32_bf16(fa1, b1, acc[1][1], 0, 0, 0);
    acc[1][2] = __builtin_amdgcn_mfma_f32_16x16x32_bf16(fa1, b2, acc[1][2], 0, 0, 0);
    acc[1][3] = __builtin_amdgcn_mfma_f32_16x16x32_bf16(fa1, b3, acc[1][3], 0, 0, 0);
  }

  const int par = l15 & 1;
  #pragma unroll
  for (int rt = 0; rt < 2; ++rt) {
    int rloc = rb + rt * 16 + quad * 4;
    int mrow = mbase + rloc;
    int4 o4;
    if (mrow + 3 < MM) {
      o4 = *(const int4*)(out_map + (size_t)k * MM + mrow);
    } else {
      o4.x = (mrow + 0 < MM) ? out_map[(size_t)k * MM + mrow + 0] : 0;
      o4.y = (mrow + 1 < MM) ? out_map[(size_t)k * MM + mrow + 1] : 0;
      o4.z = (mrow + 2 < MM) ? out_map[(size_t)k * MM + mrow + 2] : 0;
      o4.w = (mrow + 3 < MM) ? out_map[(size_t)k * MM + mrow + 3] : 0;
    }
    int om4[4] = {o4.x, o4.y, o4.z, o4.w};
    #pragma unroll
    for (int ct = 0; ct < 4; ++ct) {
      f32x4 v = acc[rt][ct];
      int colb = ct * 16 + (l15 & ~1);
      #pragma unroll
      for (int i = 0; i < 4; ++i) {
        float vn = __shfl_xor(v[i], 1);
        float lo = par ? vn : v[i];
        float hi = par ? v[i] : vn;
        unsigned pw = pack2_f16(lo, hi);
        if (((i & 1) == par) && (mrow + i < MM)) {
          const unsigned short* addr = acc16 + (size_t)om4[i] * C_OUT + colb;
          pk_atomic_f16(addr, pw);
        }
      }
    }
  }
}

// ---------- legacy fp32 fallback ----------
__global__ __launch_bounds__(256) void scatter_f32_kernel(
    const float* __restrict__ x,
    const unsigned short* __restrict__ wt,
    const int* __restrict__ in_map,
    const int* __restrict__ out_map,
    float* __restrict__ outf)
{
  __shared__ unsigned short Als[TILE_M * APAD];
  __shared__ unsigned short Bls[C_OUT * APAD];
  __shared__ int om[TILE_M];

  const int t = threadIdx.x;
  const int k = blockIdx.y;
  const int mbase = blockIdx.x * TILE_M;

  if (t < TILE_M) {
    int m = mbase + t;
    om[t] = (m < MM) ? out_map[k * MM + m] : 0;
  }
  {
    const uint4* src = (const uint4*)(wt + (size_t)k * C_OUT * C_IN);
    #pragma unroll
    for (int i = 0; i < 4; ++i) {
      int ch  = t + i * 256;
      int co  = ch >> 4;
      int ci0 = (ch & 15) * 8;
      *(uint4*)&Bls[co * APAD + ci0] = src[ch];
    }
  }
  {
    int r    = t >> 1;
    int half = t & 1;
    int m    = mbase + r;
    int src  = (m < MM) ? in_map[k * MM + m] : 0;
    const float4* xr = (const float4*)(x + (size_t)src * C_IN) + half * 16;
    uint2* dst = (uint2*)&Als[r * APAD + half * 64];
    #pragma unroll
    for (int j = 0; j < 16; ++j) {
      float4 v = xr[j];
      dst[j] = make_uint2(pack2_bf16(v.x, v.y), pack2_bf16(v.z, v.w));
    }
  }
  __syncthreads();

  const int wave = t >> 6;
  const int lane = t & 63;
  const int quad = lane >> 4;
  const int l15  = lane & 15;
  const int rb   = wave * 32;

  f32x4 acc[2][4];
  #pragma unroll
  for (int i = 0; i < 2; ++i)
    #pragma unroll
    for (int j = 0; j < 4; ++j)
      acc[i][j] = (f32x4){0.f, 0.f, 0.f, 0.f};

  #pragma unroll
  for (int kk = 0; kk < 4; ++kk) {
    const int koff = kk * 32 + quad * 8;
    bf16x8 a0 = *(const bf16x8*)&Als[(rb + l15) * APAD + koff];
    bf16x8 a1 = *(const bf16x8*)&Als[(rb + 16 + l15) * APAD + koff];
    bf16x8 b0 = *(const bf16x8*)&Bls[(l15) * APAD + koff];
    bf16x8 b1 = *(const bf16x8*)&Bls[(16 + l15) * APAD + koff];
    bf16x8 b2 = *(const bf16x8*)&Bls[(32 + l15) * APAD + koff];
    bf16x8 b3 = *(const bf16x8*)&Bls[(48 + l15) * APAD + koff];
    acc[0][0] = __builtin_amdgcn_mfma_f32_16x16x32_bf16(a0, b0, acc[0][0], 0, 0, 0);
    acc[0][1] = __builtin_amdgcn_mfma_f32_16x16x32_bf16(a0, b1, acc[0][1], 0, 0, 0);
    acc[0][2] = __builtin_amdgcn_mfma_f32_16x16x32_bf16(a0, b2, acc[0][2], 0, 0, 0);
    acc[0][3] = __builtin_amdgcn_mfma_f32_16x16x32_bf16(a0, b3, acc[0][3], 0, 0, 0);
    acc[1][0] = __builtin_amdgcn_mfma_f32_16x16x32_bf16(a1, b0, acc[1][0], 0, 0, 0);
    acc[1][1] = __builtin_amdgcn_mfma_f32_16x16x32_bf16(a1, b1, acc[1][1], 0, 0, 0);
    acc[1][2] = __builtin_amdgcn_mfma_f32_16x16x32_bf16(a1, b2, acc[1][2], 0, 0, 0);
    acc[1][3] = __builtin_amdgcn_mfma_f32_16x16x32_bf16(a1, b3, acc[1][3], 0, 0, 0);
  }

  #pragma unroll
  for (int rt = 0; rt < 2; ++rt) {
    int rloc = rb + rt * 16 + quad * 4;
    int4 o4 = *(const int4*)&om[rloc];
    int mrow = mbase + rloc;
    #pragma unroll
    for (int ct = 0; ct < 4; ++ct) {
      f32x4 v = acc[rt][ct];
      int col = ct * 16 + l15;
      if (mrow + 0 < MM) unsafeAtomicAdd(&outf[(size_t)o4.x * C_OUT + col], v[0]);
      if (mrow + 1 < MM) unsafeAtomicAdd(&outf[(size_t)o4.y * C_OUT + col], v[1]);
      if (mrow + 2 < MM) unsafeAtomicAdd(&outf[(size_t)o4.z * C_OUT + col], v[2]);
      if (mrow + 3 < MM) unsafeAtomicAdd(&outf[(size_t)o4.w * C_OUT + col], v[3]);
    }
  }
}

// ---------- f16-accumulator reductions ----------
__global__ __launch_bounds__(256) void stats16_kernel(const unsigned* __restrict__ acc,
                                                      float* __restrict__ ws) {
  __shared__ float red[4][8][32];
  int t = threadIdx.x;
  int w = t & 31, sub = t >> 5;
  float s0 = 0, q0 = 0, s1 = 0, q1 = 0;
  for (int r = blockIdx.x * 8 + sub; r < N_OUT; r += gridDim.x * 8) {
    unsigned u = acc[(size_t)r * 32 + w];
    __half2 h = *(__half2*)&u;
    float a = __low2float(h), b = __high2float(h);
    s0 += a; q0 += a * a; s1 += b; q1 += b * b;
  }
  red[0][sub][w] = s0; red[1][sub][w] = q0;
  red[2][sub][w] = s1; red[3][sub][w] = q1;
  __syncthreads();
  if (t < 32) {
    float S0 = 0, Q0 = 0, S1 = 0, Q1 = 0;
    #pragma unroll
    for (int s = 0; s < 8; ++s) {
      S0 += red[0][s][t]; Q0 += red[1][s][t];
      S1 += red[2][s][t]; Q1 += red[3][s][t];
    }
    unsafeAtomicAdd(&ws[2 * t],      S0);
    unsafeAtomicAdd(&ws[64 + 2 * t], Q0);
    unsafeAtomicAdd(&ws[2 * t + 1],      S1);
    unsafeAtomicAdd(&ws[64 + 2 * t + 1], Q1);
  }
}

__global__ void finalize16_kernel(const uint2* __restrict__ acc,
                                  float* __restrict__ out,
                                  const float* __restrict__ ws) {
  int i = blockIdx.x * 256 + threadIdx.x;
  uint2 u = acc[i];
  __half2 h0 = *(__half2*)&u.x;
  __half2 h1 = *(__half2*)&u.y;
  int c0 = (i & 15) * 4;
  float s0 = ws[128 + c0], s1 = ws[129 + c0], s2 = ws[130 + c0], s3 = ws[131 + c0];
  float b0 = ws[192 + c0], b1 = ws[193 + c0], b2 = ws[194 + c0], b3 = ws[195 + c0];
  float4 v;
  v.x = fmaxf(fmaf(__low2float(h0),  s0, b0), 0.f);
  v.y = fmaxf(fmaf(__high2float(h0), s1, b1), 0.f);
  v.z = fmaxf(fmaf(__low2float(h1),  s2, b2), 0.f);
  v.w = fmaxf(fmaf(__high2float(h1), s3, b3), 0.f);
  ((float4*)out)[i] = v;
}

// ---------- fp32 fallback reductions ----------
__global__ void stats_kernel(const float* __restrict__ out, float* __restrict__ ws) {
  __shared__ float ls[4][64];
  __shared__ float ls2[4][64];
  int t = threadIdx.x;
  int c = t & 63, sub = t >> 6;
  float s = 0.f, s2 = 0.f;
  for (int r = blockIdx.x * 4 + sub; r < N_OUT; r += gridDim.x * 4) {
    float v = out[(size_t)r * C_OUT + c];
    s += v; s2 += v * v;
  }
  ls[sub][c] = s; ls2[sub][c] = s2;
  __syncthreads();
  if (t < 64) {
    float ts = ls[0][t] + ls[1][t] + ls[2][t] + ls[3][t];
    float t2 = ls2[0][t] + ls2[1][t] + ls2[2][t] + ls2[3][t];
    unsafeAtomicAdd(&ws[t], ts);
    unsafeAtomicAdd(&ws[64 + t], t2);
  }
}

__global__ void finalize_kernel(float* __restrict__ out, const float* __restrict__ ws) {
  int i = blockIdx.x * 256 + threadIdx.x;
  float4 v = ((const float4*)out)[i];
  int c0 = (i & 15) * 4;
  float s0 = ws[128 + c0], s1 = ws[129 + c0], s2 = ws[130 + c0], s3 = ws[131 + c0];
  float b0 = ws[192 + c0], b1 = ws[193 + c0], b2 = ws[194 + c0], b3 = ws[195 + c0];
  v.x = fmaxf(fmaf(v.x, s0, b0), 0.f);
  v.y = fmaxf(fmaf(v.y, s1, b1), 0.f);
  v.z = fmaxf(fmaf(v.z, s2, b2), 0.f);
  v.w = fmaxf(fmaf(v.w, s3, b3), 0.f);
  ((float4*)out)[i] = v;
}

__global__ void prep_kernel(float* __restrict__ ws,
                            const float* __restrict__ gamma,
                            const float* __restrict__ beta) {
  int c = threadIdx.x;
  float mean = ws[c] * (1.0f / N_OUT);
  float var  = ws[64 + c] * (1.0f / N_OUT) - mean * mean;
  var = fmaxf(var, 0.0f);
  float sc = gamma[c] * rsqrtf(var + BN_EPS);
  ws[128 + c] = sc;
  ws[192 + c] = beta[c] - mean * sc;
}

extern "C" void kernel_launch(void* const* d_in, const int* in_sizes, int n_in,
                              void* d_out, int out_size, void* d_ws, size_t ws_size,
                              hipStream_t stream) {
  const float* x      = (const float*)d_in[0];
  const float* weight = (const float*)d_in[1];
  const float* gamma  = (const float*)d_in[2];
  const float* beta   = (const float*)d_in[3];
  const int* in_map   = (const int*)d_in[4];
  const int* out_map  = (const int*)d_in[5];
  float* out   = (float*)d_out;
  float* stats = (float*)d_ws;

  const size_t WT_OFF  = 4096;                       // 442 KB [k][co][ci]
  const size_t WT2_OFF = 512u * 1024;                // 442 KB fragment layout
  const size_t CNT_OFF = 1024u * 1024;               // 85 KB [buk][27]
  const size_t OFF_OFF = 1280u * 1024;               // 88 KB [buk][28]
  const size_t CUR_OFF = 1536u * 1024;               // 88 KB [buk][28]
  const size_t XB_OFF  = 2u * 1024 * 1024;           // 25.6 MB bf16 x
  const size_t REC_OFF = 28u * 1024 * 1024;          // 14.4 MB records
  const size_t REC_SZ  = (size_t)NBUK * CAP_B * 4;
  const size_t ACC_SZ  = (size_t)N_OUT * C_OUT * 2;  // 25.6 MB f16 accumulator
  const size_t ACC_MAIN = 45u * 1024 * 1024;
  const size_t NEED_MAIN = ACC_MAIN + ACC_SZ;        // ~70.6 MB
  const size_t ACC_S3   = REC_OFF;                   // scatter3: acc over rec region
  const size_t NEED_S3  = ACC_S3 + ACC_SZ;           // ~53.6 MB

  unsigned* wt  = (unsigned*)((char*)d_ws + WT_OFF);
  unsigned* wt2 = (unsigned*)((char*)d_ws + WT2_OFF);
  int* cnt      = (int*)((char*)d_ws + CNT_OFF);
  int* off      = (int*)((char*)d_ws + OFF_OFF);
  int* cur      = (int*)((char*)d_ws + CUR_OFF);
  unsigned* xb  = (unsigned*)((char*)d_ws + XB_OFF);
  unsigned* rec = (unsigned*)((char*)d_ws + REC_OFF);

  hipMemsetAsync(d_ws, 0, 1024, stream);

  if (ws_size >= NEED_MAIN) {
    unsigned short* acc16 = (unsigned short*)((char*)d_ws + ACC_MAIN);
    hipMemsetAsync(cnt, 0, (size_t)NBUK * NK * sizeof(int), stream);
    hipMemsetAsync(rec, 0x80, REC_SZ, stream);       // pad slots invalid
    hipMemsetAsync(acc16, 0, ACC_SZ, stream);
    convert_kernel<<<6682, 256, 0, stream>>>(x, xb, weight, wt, wt2, 6250);
    dim3 gm((MM + 255) / 256, NK);
    hist_in_kernel<<<gm, 256, 0, stream>>>(in_map, cnt);
    buk_scan_kernel<<<(NBUK + 3) / 4, 256, 0, stream>>>(cnt, off, cur);
    scatter_rec_in_kernel<<<gm, 256, 0, stream>>>(in_map, out_map, cur, rec);
    conv_in_kernel<<<NBUK, 256, 0, stream>>>((const uint4*)xb,
        (const uint4*)wt2, rec, off, acc16);
    stats16_kernel<<<1024, 256, 0, stream>>>((const unsigned*)acc16, stats);
    prep_kernel<<<1, 64, 0, stream>>>(stats, gamma, beta);
    finalize16_kernel<<<(N_OUT * C_OUT / 4 + 255) / 256, 256, 0, stream>>>(
        (const uint2*)acc16, out, stats);
  } else if (ws_size >= NEED_S3) {
    // round-0 proven scatter3 path
    unsigned short* acc16 = (unsigned short*)((char*)d_ws + ACC_S3);
    hipMemsetAsync(acc16, 0, ACC_SZ, stream);
    convert_kernel<<<6682, 256, 0, stream>>>(x, xb, weight, wt, wt2, 6250);
    dim3 g((MM + TILE_M - 1) / TILE_M, NK);
    scatter3_kernel<<<g, 256, 0, stream>>>((const uint4*)xb,
        (const unsigned short*)wt, in_map, out_map, acc16);
    stats16_kernel<<<1024, 256, 0, stream>>>((const unsigned*)acc16, stats);
    prep_kernel<<<1, 64, 0, stream>>>(stats, gamma, beta);
    finalize16_kernel<<<(N_OUT * C_OUT / 4 + 255) / 256, 256, 0, stream>>>(
        (const uint2*)acc16, out, stats);
  } else {
    // last-resort fp32 path
    hipMemsetAsync(d_out, 0, (size_t)N_OUT * C_OUT * sizeof(float), stream);
    convert_kernel<<<432, 256, 0, stream>>>(x, xb, weight, wt, wt2, 0);
    dim3 g((MM + TILE_M - 1) / TILE_M, NK);
    scatter_f32_kernel<<<g, 256, 0, stream>>>(x, (const unsigned short*)wt,
                                              in_map, out_map, out);
    stats_kernel<<<512, 256, 0, stream>>>(out, stats);
    prep_kernel<<<1, 64, 0, stream>>>(stats, gamma, beta);
    finalize_kernel<<<(N_OUT * C_OUT / 4 + 255) / 256, 256, 0, stream>>>(out, stats);
  }
}